// Round 4
// baseline (495.017 us; speedup 1.0000x reference)
//
#include <hip/hip_runtime.h>
#include <math.h>

#define TT 2048   // tokens
#define HH 1024   // hidden
#define EE 8      // experts
#define II 2048   // intermediate
#define N1 4096   // 2*II
#define ALPHA 1.702f
#define LIMIT 7.0f
#define MAXSCHED 40
#define SPLITK 4

typedef __attribute__((ext_vector_type(8))) short short8;
typedef __attribute__((ext_vector_type(16))) float floatx16;

#define GLL(g, l) __builtin_amdgcn_global_load_lds(                          \
    (const __attribute__((address_space(1))) void*)(g),                      \
    (__attribute__((address_space(3))) void*)(l), 16, 0, 0)

__device__ __forceinline__ short f2bf(float f) {
  union { float f; unsigned u; } v; v.f = f;
  unsigned r = (v.u + 0x7fffu + ((v.u >> 16) & 1u)) >> 16;
  return (short)r;
}
__device__ __forceinline__ float bf2f(unsigned short s) {
  union { unsigned u; float f; } v; v.u = ((unsigned)s) << 16;
  return v.f;
}

// ---------------- x f32 -> bf16 ----------------
__global__ __launch_bounds__(256) void convert_x(const float* __restrict__ x,
                                                 unsigned short* __restrict__ xb) {
  const size_t off = ((size_t)blockIdx.x * blockDim.x + threadIdx.x) * 8;
  const float4 v0 = *(const float4*)(x + off);
  const float4 v1 = *(const float4*)(x + off + 4);
  short8 s;
  s[0]=f2bf(v0.x); s[1]=f2bf(v0.y); s[2]=f2bf(v0.z); s[3]=f2bf(v0.w);
  s[4]=f2bf(v1.x); s[5]=f2bf(v1.y); s[6]=f2bf(v1.z); s[7]=f2bf(v1.w);
  *(short8*)(xb + off) = s;
}

// ---------------- router: logits -> softmax -> top2 ----------------
__global__ __launch_bounds__(256) void router_kernel(
    const float* __restrict__ x, const float* __restrict__ rw,
    const float* __restrict__ rb, int* __restrict__ topk_idx,
    float* __restrict__ topk_w) {
  const int t = blockIdx.x;
  const float* xr = x + (size_t)t * HH;
  const int lane = threadIdx.x & 63;
  const int wave = threadIdx.x >> 6;
  float xv[16];
#pragma unroll
  for (int i = 0; i < 16; i++) xv[i] = xr[lane + i * 64];
  __shared__ float logits[EE];
#pragma unroll
  for (int ee = 0; ee < 2; ee++) {
    const int e = wave * 2 + ee;
    const float* wr = rw + (size_t)e * HH;
    float s = 0.f;
#pragma unroll
    for (int i = 0; i < 16; i++) s += xv[i] * wr[lane + i * 64];
#pragma unroll
    for (int off = 32; off > 0; off >>= 1) s += __shfl_down(s, off, 64);
    if (lane == 0) logits[e] = s + rb[e];
  }
  __syncthreads();
  if (threadIdx.x == 0) {
    float sc[EE];
    float mx = -3.4e38f;
    for (int i = 0; i < EE; i++) mx = fmaxf(mx, logits[i]);
    float sum = 0.f;
    for (int i = 0; i < EE; i++) { sc[i] = expf(logits[i] - mx); sum += sc[i]; }
    const float inv = 1.f / sum;
    int i0 = 0;
    for (int i = 1; i < EE; i++) if (sc[i] > sc[i0]) i0 = i;
    int i1 = (i0 == 0) ? 1 : 0;
    for (int i = 0; i < EE; i++) if (i != i0 && sc[i] > sc[i1]) i1 = i;
    topk_idx[t * 2 + 0] = i0;
    topk_idx[t * 2 + 1] = i1;
    topk_w[t * 2 + 0] = sc[i0] * inv;
    topk_w[t * 2 + 1] = sc[i1] * inv;
  }
}

// ---------------- token->expert compaction + schedule ----------------
__global__ void assign_kernel(const int* __restrict__ topk_idx,
                              int* __restrict__ counts, int* __restrict__ rows) {
  const int id = blockIdx.x * blockDim.x + threadIdx.x;
  if (id >= TT * 2) return;
  const int e = topk_idx[id];
  const int slot = atomicAdd(&counts[e], 1);
  rows[e * TT + slot] = id;  // entry = t*2 + k
}

__global__ void sched_kernel(const int* __restrict__ counts,
                             int* __restrict__ sched, int* __restrict__ nsched) {
  if (threadIdx.x == 0) {
    int n = 0;
    for (int e = 0; e < EE; e++) {
      const int mt = (counts[e] + 127) >> 7;
      for (int m = 0; m < mt; m++) sched[n++] = (e << 8) | m;
    }
    nsched[0] = n;
  }
}

// ====== GEMM1 fused: A(x_bf, LDS via GLL) x B(gup f32 direct) -> act (bf16) ======
// 32x32x16 MFMA. Block: 128 m x (64 gate + 64 up cols). ntile covers act cols
// [ntile*64, ntile*64+64).
__global__ __launch_bounds__(256, 4) void gemm_gu(
    const unsigned short* __restrict__ x_bf,
    const float* __restrict__ gup,
    const float* __restrict__ gub,
    const int* __restrict__ counts, const int* __restrict__ rows,
    const int* __restrict__ sched, const int* __restrict__ nsched,
    unsigned short* __restrict__ act) {
  const int sid = blockIdx.y;
  if (sid >= nsched[0]) return;
  const int sv = sched[sid];
  const int e = sv >> 8, mtile = sv & 255;
  const int count = counts[e] - mtile * 128;
  const int ntile = blockIdx.x;
  const int* rl = rows + e * TT + mtile * 128;

  __shared__ short As[128 * 128];  // [m][k-chunk 128], 16B slot s holds octet s^(m&15)

  const int tid = threadIdx.x;
  const int lane = tid & 63, wave = tid >> 6;
  const int half = lane >> 5, n32 = lane & 31;
  const int wm = (wave & 1) << 6;            // m offset: {0,64}
  const int wh = (wave >> 1) << 5;           // act-col half offset: {0,32}

  // A staging sources (GLL): wave stages rows [wave*32, wave*32+32)
  const unsigned short* asrc[8];
#pragma unroll
  for (int p = 0; p < 8; p++) {
    const int m = wave * 32 + p * 4 + (lane >> 4);
    const int cm = (m < count) ? m : 0;
    const int g = (lane & 15) ^ (m & 15);
    asrc[p] = x_bf + (size_t)(rl[cm] >> 1) * HH + g * 8;
  }

  // B columns: nf=0 -> gate col, nf=1 -> up col (same local col index)
  const int acol = wh + n32;                     // 0..63 local act col
  const int colf[2] = { ntile * 64 + acol, II + ntile * 64 + acol };
  const float* bbase = gup + (size_t)e * HH * N1;

  floatx16 acc[2][2] = {};

  for (int c = 0; c < 8; c++) {   // 8 chunks of 128 k
    __syncthreads();
#pragma unroll
    for (int p = 0; p < 8; p++)
      GLL(asrc[p] + c * 128, &As[(wave * 32 + p * 4) * 128]);
    __syncthreads();
#pragma unroll 2
    for (int kt = 0; kt < 8; kt++) {   // K=16 per step
      short8 af[2];
#pragma unroll
      for (int i = 0; i < 2; i++) {
        const int m = wm + i * 32 + n32;
        const int sl = (kt * 2 + half) ^ (m & 15);
        af[i] = *(const short8*)&As[m * 128 + sl * 8];
      }
      const float* bp0 = bbase + (size_t)(c * 128 + kt * 16 + half * 8) * N1;
#pragma unroll
      for (int nf = 0; nf < 2; nf++) {
        float bv[8];
#pragma unroll
        for (int j = 0; j < 8; j++) bv[j] = bp0[j * N1 + colf[nf]];
        union { unsigned u[4]; short8 s8; } bp;
#pragma unroll
        for (int j = 0; j < 4; j++)
          bp.u[j] = __builtin_amdgcn_perm(__float_as_uint(bv[2 * j + 1]),
                                          __float_as_uint(bv[2 * j]), 0x07060302u);
#pragma unroll
        for (int i = 0; i < 2; i++)
          acc[i][nf] = __builtin_amdgcn_mfma_f32_32x32x16_bf16(af[i], bp.s8, acc[i][nf], 0, 0, 0);
      }
    }
  }

  // epilogue: act = (clip(up+bu,-L,L)+1) * silu_glu(min(gate+bg, L))
  const float bg = gub[(size_t)e * N1 + ntile * 64 + acol];
  const float bu = gub[(size_t)e * N1 + II + ntile * 64 + acol];
#pragma unroll
  for (int i = 0; i < 2; i++) {
#pragma unroll
    for (int reg = 0; reg < 16; reg++) {
      const int r = wm + i * 32 + (reg & 3) + 8 * (reg >> 2) + 4 * half;
      if (r < count) {
        const int ent = rl[r];
        float g = acc[i][0][reg] + bg;
        float u = acc[i][1][reg] + bu;
        g = fminf(g, LIMIT);
        u = fminf(fmaxf(u, -LIMIT), LIMIT);
        const float glu = g / (1.f + expf(-g * ALPHA));
        act[(size_t)ent * II + ntile * 64 + acol] = (unsigned short)f2bf((u + 1.f) * glu);
      }
    }
  }
}

// ====== GEMM2: A(act, LDS via GLL) x B(dp f32 direct) -> dout[split] (f32) ======
__global__ __launch_bounds__(256, 4) void gemm_down(
    const unsigned short* __restrict__ act,
    const float* __restrict__ dp,
    const int* __restrict__ counts, const int* __restrict__ rows,
    const int* __restrict__ sched, const int* __restrict__ nsched,
    float* __restrict__ dout) {
  const int sid = blockIdx.y;
  if (sid >= nsched[0]) return;
  const int sv = sched[sid];
  const int e = sv >> 8, mtile = sv & 255;
  const int count = counts[e] - mtile * 128;
  const int ntile = blockIdx.x;
  const int split = blockIdx.z;
  const int kbase = split * (II / SPLITK);
  const int* rl = rows + e * TT + mtile * 128;

  __shared__ short As[128 * 128];

  const int tid = threadIdx.x;
  const int lane = tid & 63, wave = tid >> 6;
  const int half = lane >> 5, n32 = lane & 31;
  const int wm = (wave & 1) << 6;
  const int wn = (wave >> 1) << 6;

  const unsigned short* asrc[8];
#pragma unroll
  for (int p = 0; p < 8; p++) {
    const int m = wave * 32 + p * 4 + (lane >> 4);
    const int cm = (m < count) ? m : 0;
    const int g = (lane & 15) ^ (m & 15);
    asrc[p] = act + (size_t)rl[cm] * II + kbase + g * 8;
  }

  const int colf[2] = { ntile * 128 + wn + n32, ntile * 128 + wn + 32 + n32 };
  const float* bbase = dp + (size_t)e * II * HH;

  floatx16 acc[2][2] = {};

  for (int c = 0; c < II / SPLITK / 128; c++) {   // 4 chunks of 128 k
    __syncthreads();
#pragma unroll
    for (int p = 0; p < 8; p++)
      GLL(asrc[p] + c * 128, &As[(wave * 32 + p * 4) * 128]);
    __syncthreads();
#pragma unroll 2
    for (int kt = 0; kt < 8; kt++) {
      short8 af[2];
#pragma unroll
      for (int i = 0; i < 2; i++) {
        const int m = wm + i * 32 + n32;
        const int sl = (kt * 2 + half) ^ (m & 15);
        af[i] = *(const short8*)&As[m * 128 + sl * 8];
      }
      const float* bp0 = bbase + (size_t)(kbase + c * 128 + kt * 16 + half * 8) * HH;
#pragma unroll
      for (int nf = 0; nf < 2; nf++) {
        float bv[8];
#pragma unroll
        for (int j = 0; j < 8; j++) bv[j] = bp0[j * HH + colf[nf]];
        union { unsigned u[4]; short8 s8; } bp;
#pragma unroll
        for (int j = 0; j < 4; j++)
          bp.u[j] = __builtin_amdgcn_perm(__float_as_uint(bv[2 * j + 1]),
                                          __float_as_uint(bv[2 * j]), 0x07060302u);
#pragma unroll
        for (int i = 0; i < 2; i++)
          acc[i][nf] = __builtin_amdgcn_mfma_f32_32x32x16_bf16(af[i], bp.s8, acc[i][nf], 0, 0, 0);
      }
    }
  }

  float* dsl = dout + (size_t)split * (TT * 2) * HH;
#pragma unroll
  for (int i = 0; i < 2; i++) {
#pragma unroll
    for (int reg = 0; reg < 16; reg++) {
      const int r = wm + i * 32 + (reg & 3) + 8 * (reg >> 2) + 4 * half;
      if (r < count) {
        const int ent = rl[r];
#pragma unroll
        for (int nf = 0; nf < 2; nf++)
          dsl[(size_t)ent * HH + colf[nf]] = acc[i][nf][reg];
      }
    }
  }
}

// -------- combine: out[t] = sum_k w_k * (sum_s dout[s][t*2+k] + db[e_k]) --------
__global__ __launch_bounds__(256) void combine_kernel(
    const float* __restrict__ dout, const float* __restrict__ tw,
    const int* __restrict__ tidx, const float* __restrict__ db,
    float* __restrict__ out) {
  const int id = blockIdx.x * blockDim.x + threadIdx.x;
  const int t = id >> 8;
  const int h = (id & 255) * 4;
  float4 o = {0.f, 0.f, 0.f, 0.f};
#pragma unroll
  for (int k = 0; k < 2; k++) {
    const float w = tw[t * 2 + k];
    const int e = tidx[t * 2 + k];
    const float4 bb = *(const float4*)(db + (size_t)e * HH + h);
    float4 s = bb;
#pragma unroll
    for (int sp = 0; sp < SPLITK; sp++) {
      const float4 d = *(const float4*)(dout +
          ((size_t)sp * (TT * 2) + t * 2 + k) * HH + h);
      s.x += d.x; s.y += d.y; s.z += d.z; s.w += d.w;
    }
    o.x += w * s.x; o.y += w * s.y; o.z += w * s.z; o.w += w * s.w;
  }
  *(float4*)(out + (size_t)t * HH + h) = o;
}

extern "C" void kernel_launch(void* const* d_in, const int* in_sizes, int n_in,
                              void* d_out, int out_size, void* d_ws, size_t ws_size,
                              hipStream_t stream) {
  const float* x   = (const float*)d_in[0];
  const float* rw  = (const float*)d_in[1];
  const float* rb  = (const float*)d_in[2];
  const float* gup = (const float*)d_in[3];
  const float* gub = (const float*)d_in[4];
  const float* dp  = (const float*)d_in[5];
  const float* db  = (const float*)d_in[6];
  float* out = (float*)d_out;

  char* ws = (char*)d_ws;
  int*   topk_idx = (int*)(ws + 0);            // 16 KB
  float* topk_w   = (float*)(ws + 16384);      // 16 KB
  int*   counts   = (int*)(ws + 32768);        // 256 B
  int*   nsched   = (int*)(ws + 33024);        // 256 B
  int*   sched    = (int*)(ws + 33280);        // 256 B
  int*   rows     = (int*)(ws + 36864);        // 64 KB
  unsigned short* x_bf = (unsigned short*)(ws + (1u << 20));   // 4 MB
  unsigned short* act  = (unsigned short*)(ws + 6291456);      // 16.8 MB
  float*          dout = (float*)(ws + 23068672);              // 67.1 MB (4 splits)
  // total ~90 MB

  convert_x<<<TT * HH / (256 * 8), 256, 0, stream>>>(x, x_bf);
  router_kernel<<<TT, 256, 0, stream>>>(x, rw, rb, topk_idx, topk_w);
  hipMemsetAsync(counts, 0, 64, stream);
  assign_kernel<<<(TT * 2 + 255) / 256, 256, 0, stream>>>(topk_idx, counts, rows);
  sched_kernel<<<1, 64, 0, stream>>>(counts, sched, nsched);
  gemm_gu<<<dim3(II / 64, MAXSCHED), 256, 0, stream>>>(
      x_bf, gup, gub, counts, rows, sched, nsched, act);
  gemm_down<<<dim3(HH / 128, MAXSCHED, SPLITK), 256, 0, stream>>>(
      act, dp, counts, rows, sched, nsched, dout);
  combine_kernel<<<(TT * HH / 4) / 256, 256, 0, stream>>>(dout, topk_w, topk_idx, db, out);
}